// Round 1
// baseline (304.175 us; speedup 1.0000x reference)
//
#include <hip/hip_runtime.h>
#include <hip/hip_bf16.h>

// ---------------------------------------------------------------------------
// AAttn (area attention) fused pipeline for MI355X (gfx950)
//  x:(4,256,64,64) -> qkv conv1x1 -> attention (16 areas x 8 heads, Na=1024,
//  hd=32) -> + dwconv7(v) -> proj conv1x1 -> out:(4,256,64,64)
// Workspace: QKV fp32 [16384][768] (50.3MB) + AOUT fp32 [16384][256] (16.8MB)
// ---------------------------------------------------------------------------

typedef __attribute__((ext_vector_type(8))) short bf16x8;
typedef __attribute__((ext_vector_type(4))) float f32x4;

__device__ __forceinline__ short f2bf(float f) {
    unsigned u = __builtin_bit_cast(unsigned, f);
    u = u + 0x7fffu + ((u >> 16) & 1u);   // RNE
    return (short)(u >> 16);
}

__device__ __forceinline__ float fexp2(float x) {
#if __has_builtin(__builtin_amdgcn_exp2f)
    return __builtin_amdgcn_exp2f(x);
#else
    return exp2f(x);
#endif
}

// ---------------------------------------------------------------------------
// Kernel 1: QKV GEMM.  out[R=16384][col=768] = sum_c x[b][c][n] * W[col][c]
// A = X^T (strided channel access, staged+transposed via LDS), B = W^T.
// block 256 thr (4 waves), tile 64x64, BK=32.
// ---------------------------------------------------------------------------
__global__ __launch_bounds__(256) void qkv_gemm(const float* __restrict__ X,
                                                const float* __restrict__ W,
                                                const float* __restrict__ bias,
                                                float* __restrict__ out) {
    __shared__ short Alds[64][40];   // [row(n)][k(c)]  pad->40 to break conflicts
    __shared__ short Blds[64][40];   // [col][k]
    const int t = threadIdx.x;
    const int wv = t >> 6, lane = t & 63;
    const int g = lane >> 4, cc = lane & 15;
    const int R0 = blockIdx.x * 64;
    const int b = R0 >> 12, n0 = R0 & 4095;
    const int col0 = blockIdx.y * 64;
    f32x4 acc[4] = {};

    const int a_kk = t >> 4;          // 0..15 (k within tile, x2 iters)
    const int a_ii = (t & 15) * 4;    // 0..60 (row)
    const int b_col = t >> 2;         // 0..63
    const int b_kp  = (t & 3) * 8;    // 0,8,16,24

    for (int k0 = 0; k0 < 256; k0 += 32) {
        __syncthreads();
        // stage A: read x rows (contiguous in n), write transposed to LDS
        #pragma unroll
        for (int it = 0; it < 2; ++it) {
            const int kk = a_kk + it * 16;
            const float4 v = *reinterpret_cast<const float4*>(
                X + (((size_t)(b * 256 + k0 + kk)) << 12) + n0 + a_ii);
            Alds[a_ii + 0][kk] = f2bf(v.x);
            Alds[a_ii + 1][kk] = f2bf(v.y);
            Alds[a_ii + 2][kk] = f2bf(v.z);
            Alds[a_ii + 3][kk] = f2bf(v.w);
        }
        // stage B: W[col][k] rows contiguous in k
        {
            const float* wp = W + (size_t)(col0 + b_col) * 256 + k0 + b_kp;
            const float4 v0 = *reinterpret_cast<const float4*>(wp);
            const float4 v1 = *reinterpret_cast<const float4*>(wp + 4);
            bf16x8 pk;
            pk[0] = f2bf(v0.x); pk[1] = f2bf(v0.y); pk[2] = f2bf(v0.z); pk[3] = f2bf(v0.w);
            pk[4] = f2bf(v1.x); pk[5] = f2bf(v1.y); pk[6] = f2bf(v1.z); pk[7] = f2bf(v1.w);
            *reinterpret_cast<bf16x8*>(&Blds[b_col][b_kp]) = pk;
        }
        __syncthreads();
        const bf16x8 af = *reinterpret_cast<const bf16x8*>(&Alds[wv * 16 + cc][g * 8]);
        #pragma unroll
        for (int nt = 0; nt < 4; ++nt) {
            const bf16x8 bfr = *reinterpret_cast<const bf16x8*>(&Blds[nt * 16 + cc][g * 8]);
            acc[nt] = __builtin_amdgcn_mfma_f32_16x16x32_bf16(af, bfr, acc[nt], 0, 0, 0);
        }
    }
    #pragma unroll
    for (int nt = 0; nt < 4; ++nt) {
        const int col = col0 + nt * 16 + cc;
        const float bv = bias[col];
        #pragma unroll
        for (int r = 0; r < 4; ++r) {
            const int row = R0 + wv * 16 + g * 4 + r;
            out[(size_t)row * 768 + col] = acc[nt][r] + bv;
        }
    }
}

// ---------------------------------------------------------------------------
// Kernel 2: flash attention per (ba, head, 64-q chunk). 4 waves x 16 q rows.
// QKV row R = ba*1024 + n holds [h*96 +0:q +32:k +64:v].
// ---------------------------------------------------------------------------
__global__ __launch_bounds__(256) void attn_kernel(const float* __restrict__ QKV,
                                                   float* __restrict__ aout) {
    __shared__ short Klds[32][40];      // [key][d]
    __shared__ short Vlds[32][40];      // [d][key]  (transposed for B-frag)
    __shared__ short Plds[4][16][40];   // per-wave [q][key]
    const int t = threadIdx.x;
    const int wv = t >> 6, lane = t & 63;
    const int g = lane >> 4, cc = lane & 15;
    const int qc = blockIdx.x;   // 0..15
    const int h  = blockIdx.y;   // 0..7
    const int ba = blockIdx.z;   // 0..15
    // 1/sqrt(32) * log2(e): do softmax in base-2
    const float SCALE = 0.17677669529663687f * 1.44269504088896340736f;

    // Q fragment (A): lane holds row cc, k = g*8..g*8+7 (hd=32 == MFMA K)
    const float* qp = QKV + (size_t)(ba * 1024 + qc * 64 + wv * 16 + cc) * 768 + h * 96 + g * 8;
    bf16x8 qf;
    #pragma unroll
    for (int j = 0; j < 8; ++j) qf[j] = f2bf(qp[j] * SCALE);

    f32x4 o0 = {}, o1 = {};
    float mrow[4] = {-3e38f, -3e38f, -3e38f, -3e38f};
    float lrow[4] = {0.f, 0.f, 0.f, 0.f};

    const int s_key = t >> 3;        // 0..31
    const int s_dp  = (t & 7) * 4;   // 0..28

    for (int kt = 0; kt < 32; ++kt) {
        __syncthreads();
        const float* kp = QKV + (size_t)(ba * 1024 + kt * 32 + s_key) * 768 + h * 96 + 32 + s_dp;
        const float4 kv = *reinterpret_cast<const float4*>(kp);
        const float4 vv = *reinterpret_cast<const float4*>(kp + 32);
        Klds[s_key][s_dp + 0] = f2bf(kv.x);
        Klds[s_key][s_dp + 1] = f2bf(kv.y);
        Klds[s_key][s_dp + 2] = f2bf(kv.z);
        Klds[s_key][s_dp + 3] = f2bf(kv.w);
        Vlds[s_dp + 0][s_key] = f2bf(vv.x);
        Vlds[s_dp + 1][s_key] = f2bf(vv.y);
        Vlds[s_dp + 2][s_key] = f2bf(vv.z);
        Vlds[s_dp + 3][s_key] = f2bf(vv.w);
        __syncthreads();

        // S = Q*K^T : two 16x16 tiles (keys 0..15, 16..31), K-contraction = hd = 32
        const bf16x8 kf0 = *reinterpret_cast<const bf16x8*>(&Klds[cc][g * 8]);
        const bf16x8 kf1 = *reinterpret_cast<const bf16x8*>(&Klds[16 + cc][g * 8]);
        const f32x4 z = {};
        f32x4 s0 = __builtin_amdgcn_mfma_f32_16x16x32_bf16(qf, kf0, z, 0, 0, 0);
        f32x4 s1 = __builtin_amdgcn_mfma_f32_16x16x32_bf16(qf, kf1, z, 0, 0, 0);

        // row max over the 32 keys: D-frag rows q=g*4+r, cols spread over 16 lanes
        float mt[4];
        #pragma unroll
        for (int r = 0; r < 4; ++r) mt[r] = fmaxf(s0[r], s1[r]);
        #pragma unroll
        for (int msk = 1; msk <= 8; msk <<= 1) {
            #pragma unroll
            for (int r = 0; r < 4; ++r) mt[r] = fmaxf(mt[r], __shfl_xor(mt[r], msk, 64));
        }
        f32x4 p0, p1;
        float rs[4], fac[4];
        #pragma unroll
        for (int r = 0; r < 4; ++r) {
            const float mn = fmaxf(mrow[r], mt[r]);
            fac[r] = fexp2(mrow[r] - mn);
            mrow[r] = mn;
            p0[r] = fexp2(s0[r] - mn);
            p1[r] = fexp2(s1[r] - mn);
            rs[r] = p0[r] + p1[r];
        }
        #pragma unroll
        for (int msk = 1; msk <= 8; msk <<= 1) {
            #pragma unroll
            for (int r = 0; r < 4; ++r) rs[r] += __shfl_xor(rs[r], msk, 64);
        }
        #pragma unroll
        for (int r = 0; r < 4; ++r) {
            lrow[r] = lrow[r] * fac[r] + rs[r];
            o0[r] *= fac[r];
            o1[r] *= fac[r];
            // P -> per-wave LDS (D-layout write), re-read as PV A-fragment
            Plds[wv][g * 4 + r][cc]      = f2bf(p0[r]);
            Plds[wv][g * 4 + r][16 + cc] = f2bf(p1[r]);
        }
        const bf16x8 pf  = *reinterpret_cast<const bf16x8*>(&Plds[wv][cc][g * 8]);
        const bf16x8 vf0 = *reinterpret_cast<const bf16x8*>(&Vlds[cc][g * 8]);
        const bf16x8 vf1 = *reinterpret_cast<const bf16x8*>(&Vlds[16 + cc][g * 8]);
        o0 = __builtin_amdgcn_mfma_f32_16x16x32_bf16(pf, vf0, o0, 0, 0, 0);
        o1 = __builtin_amdgcn_mfma_f32_16x16x32_bf16(pf, vf1, o1, 0, 0, 0);
    }

    #pragma unroll
    for (int r = 0; r < 4; ++r) {
        const float inv = 1.f / lrow[r];
        const int q = qc * 64 + wv * 16 + g * 4 + r;
        float* op = aout + (size_t)(ba * 1024 + q) * 256 + h * 32;
        op[cc]      = o0[r] * inv;
        op[16 + cc] = o1[r] * inv;
    }
}

// ---------------------------------------------------------------------------
// Kernel 3: aout += dwconv7(V) + b_pe.  V channel c lives at QKV col
// (c>>5)*96 + 64 + (c&31).  block = 256 threads (one per channel), 8
// consecutive x positions per block.
// ---------------------------------------------------------------------------
__global__ __launch_bounds__(256) void pe_add(const float* __restrict__ QKV,
                                              const float* __restrict__ wpe,
                                              const float* __restrict__ bpe,
                                              float* __restrict__ aout) {
    const int c = threadIdx.x;
    const int R0 = blockIdx.x * 8;
    const int b = R0 >> 12;
    const int n0 = R0 & 4095;
    const int y = n0 >> 6, x0 = n0 & 63;
    const int col = (c >> 5) * 96 + 64 + (c & 31);
    const float bias = bpe[c];
    float w[49];
    #pragma unroll
    for (int i = 0; i < 49; ++i) w[i] = wpe[c * 49 + i];

    for (int p = 0; p < 8; ++p) {
        const int x = x0 + p;
        float acc = aout[(size_t)(R0 + p) * 256 + c] + bias;
        #pragma unroll
        for (int dy = 0; dy < 7; ++dy) {
            const int yy = y + dy - 3;
            if ((unsigned)yy < 64u) {
                #pragma unroll
                for (int dx = 0; dx < 7; ++dx) {
                    const int xx = x + dx - 3;
                    if ((unsigned)xx < 64u) {
                        acc += w[dy * 7 + dx] *
                               QKV[(size_t)(b * 4096 + yy * 64 + xx) * 768 + col];
                    }
                }
            }
        }
        aout[(size_t)(R0 + p) * 256 + c] = acc;
    }
}

// ---------------------------------------------------------------------------
// Kernel 4: proj GEMM.  out[b][c][n] = sum_k aout[R][k]*Wp[c][k] + bp[c]
// tile 64x64; coalesced store via LDS transpose (pad 65 to kill conflicts).
// ---------------------------------------------------------------------------
__global__ __launch_bounds__(256) void proj_gemm(const float* __restrict__ A,
                                                 const float* __restrict__ W,
                                                 const float* __restrict__ bias,
                                                 float* __restrict__ out) {
    __shared__ union {
        struct { short A[64][40]; short B[64][40]; } s;
        float T[64][65];
    } u;
    const int t = threadIdx.x;
    const int wv = t >> 6, lane = t & 63;
    const int g = lane >> 4, cc = lane & 15;
    const int R0 = blockIdx.x * 64;
    const int b = R0 >> 12, n0 = R0 & 4095;
    const int col0 = blockIdx.y * 64;
    const int a_i  = t >> 2;          // 0..63
    const int a_kp = (t & 3) * 8;     // 0,8,16,24
    f32x4 acc[4] = {};

    for (int k0 = 0; k0 < 256; k0 += 32) {
        __syncthreads();
        {
            const float* ap = A + (size_t)(R0 + a_i) * 256 + k0 + a_kp;
            const float4 v0 = *reinterpret_cast<const float4*>(ap);
            const float4 v1 = *reinterpret_cast<const float4*>(ap + 4);
            bf16x8 pk;
            pk[0] = f2bf(v0.x); pk[1] = f2bf(v0.y); pk[2] = f2bf(v0.z); pk[3] = f2bf(v0.w);
            pk[4] = f2bf(v1.x); pk[5] = f2bf(v1.y); pk[6] = f2bf(v1.z); pk[7] = f2bf(v1.w);
            *reinterpret_cast<bf16x8*>(&u.s.A[a_i][a_kp]) = pk;

            const float* wp = W + (size_t)(col0 + a_i) * 256 + k0 + a_kp;
            const float4 w0 = *reinterpret_cast<const float4*>(wp);
            const float4 w1 = *reinterpret_cast<const float4*>(wp + 4);
            bf16x8 pw;
            pw[0] = f2bf(w0.x); pw[1] = f2bf(w0.y); pw[2] = f2bf(w0.z); pw[3] = f2bf(w0.w);
            pw[4] = f2bf(w1.x); pw[5] = f2bf(w1.y); pw[6] = f2bf(w1.z); pw[7] = f2bf(w1.w);
            *reinterpret_cast<bf16x8*>(&u.s.B[a_i][a_kp]) = pw;
        }
        __syncthreads();
        const bf16x8 af = *reinterpret_cast<const bf16x8*>(&u.s.A[wv * 16 + cc][g * 8]);
        #pragma unroll
        for (int nt = 0; nt < 4; ++nt) {
            const bf16x8 bfr = *reinterpret_cast<const bf16x8*>(&u.s.B[nt * 16 + cc][g * 8]);
            acc[nt] = __builtin_amdgcn_mfma_f32_16x16x32_bf16(af, bfr, acc[nt], 0, 0, 0);
        }
    }
    __syncthreads();   // frag reads done before overwriting LDS as T
    #pragma unroll
    for (int nt = 0; nt < 4; ++nt) {
        const float bv = bias[col0 + nt * 16 + cc];
        #pragma unroll
        for (int r = 0; r < 4; ++r)
            u.T[nt * 16 + cc][wv * 16 + g * 4 + r] = acc[nt][r] + bv;
    }
    __syncthreads();
    #pragma unroll
    for (int it = 0; it < 16; ++it) {
        const int idx = it * 256 + t;
        const int ccc = idx >> 6, rr = idx & 63;
        out[(((size_t)(b * 256 + col0 + ccc)) << 12) + n0 + rr] = u.T[ccc][rr];
    }
}

// ---------------------------------------------------------------------------
extern "C" void kernel_launch(void* const* d_in, const int* in_sizes, int n_in,
                              void* d_out, int out_size, void* d_ws, size_t ws_size,
                              hipStream_t stream) {
    const float* x      = (const float*)d_in[0];
    const float* w_qkv  = (const float*)d_in[1];
    const float* b_qkv  = (const float*)d_in[2];
    const float* w_pe   = (const float*)d_in[3];
    const float* b_pe   = (const float*)d_in[4];
    const float* w_proj = (const float*)d_in[5];
    const float* b_proj = (const float*)d_in[6];
    float* out = (float*)d_out;

    float* qkvbuf = (float*)d_ws;                       // [16384][768]
    float* aout   = qkvbuf + (size_t)16384 * 768;       // [16384][256]

    qkv_gemm<<<dim3(256, 12), 256, 0, stream>>>(x, w_qkv, b_qkv, qkvbuf);
    attn_kernel<<<dim3(16, 8, 16), 256, 0, stream>>>(qkvbuf, aout);
    pe_add<<<2048, 256, 0, stream>>>(qkvbuf, w_pe, b_pe, aout);
    proj_gemm<<<dim3(256, 4), 256, 0, stream>>>(aout, w_proj, b_proj, out);
}

// Round 2
// 199.438 us; speedup vs baseline: 1.5252x; 1.5252x over previous
//
#include <hip/hip_runtime.h>
#include <hip/hip_bf16.h>

// ---------------------------------------------------------------------------
// AAttn (area attention) fused pipeline for MI355X (gfx950)
//  x:(4,256,64,64) -> qkv conv1x1 (bf16 out) -> attention (16 areas x 8 heads,
//  Na=1024, hd=32, swapped-operand MFMA flash) -> + dwconv7(v) -> proj conv1x1
// Workspace: QKV bf16 [16384][768] (25.2MB) + AOUT fp32 [16384][256] (16.8MB)
// ---------------------------------------------------------------------------

typedef __attribute__((ext_vector_type(8))) short bf16x8;
typedef __attribute__((ext_vector_type(4))) short bf16x4;
typedef __attribute__((ext_vector_type(8))) unsigned short u16x8;
typedef __attribute__((ext_vector_type(4))) float f32x4;
typedef unsigned short u16;

__device__ __forceinline__ short f2bf(float f) {
    unsigned u = __builtin_bit_cast(unsigned, f);
    u = u + 0x7fffu + ((u >> 16) & 1u);   // RNE
    return (short)(u >> 16);
}
__device__ __forceinline__ float bf2f(u16 u) {
    return __builtin_bit_cast(float, (unsigned)u << 16);
}
__device__ __forceinline__ float fexp2(float x) {
#if __has_builtin(__builtin_amdgcn_exp2f)
    return __builtin_amdgcn_exp2f(x);
#else
    return exp2f(x);
#endif
}
__device__ __forceinline__ unsigned cvt_pk_bf16(float lo, float hi) {
    unsigned r;
    asm("v_cvt_pk_bf16_f32 %0, %1, %2" : "=v"(r) : "v"(lo), "v"(hi));
    return r;
}

// ---------------------------------------------------------------------------
// Kernel 1: QKV GEMM -> bf16.  out[R=16384][col=768] = sum_c x[b][c][n]*W[col][c]
// ---------------------------------------------------------------------------
__global__ __launch_bounds__(256) void qkv_gemm(const float* __restrict__ X,
                                                const float* __restrict__ W,
                                                const float* __restrict__ bias,
                                                u16* __restrict__ out) {
    __shared__ short Alds[64][40];
    __shared__ short Blds[64][40];
    const int t = threadIdx.x;
    const int wv = t >> 6, lane = t & 63;
    const int g = lane >> 4, cc = lane & 15;
    const int R0 = blockIdx.x * 64;
    const int b = R0 >> 12, n0 = R0 & 4095;
    const int col0 = blockIdx.y * 64;
    f32x4 acc[4] = {};

    const int a_kk = t >> 4;
    const int a_ii = (t & 15) * 4;
    const int b_col = t >> 2;
    const int b_kp  = (t & 3) * 8;

    for (int k0 = 0; k0 < 256; k0 += 32) {
        __syncthreads();
        #pragma unroll
        for (int it = 0; it < 2; ++it) {
            const int kk = a_kk + it * 16;
            const float4 v = *reinterpret_cast<const float4*>(
                X + (((size_t)(b * 256 + k0 + kk)) << 12) + n0 + a_ii);
            Alds[a_ii + 0][kk] = f2bf(v.x);
            Alds[a_ii + 1][kk] = f2bf(v.y);
            Alds[a_ii + 2][kk] = f2bf(v.z);
            Alds[a_ii + 3][kk] = f2bf(v.w);
        }
        {
            const float* wp = W + (size_t)(col0 + b_col) * 256 + k0 + b_kp;
            const float4 v0 = *reinterpret_cast<const float4*>(wp);
            const float4 v1 = *reinterpret_cast<const float4*>(wp + 4);
            bf16x8 pk;
            pk[0] = f2bf(v0.x); pk[1] = f2bf(v0.y); pk[2] = f2bf(v0.z); pk[3] = f2bf(v0.w);
            pk[4] = f2bf(v1.x); pk[5] = f2bf(v1.y); pk[6] = f2bf(v1.z); pk[7] = f2bf(v1.w);
            *reinterpret_cast<bf16x8*>(&Blds[b_col][b_kp]) = pk;
        }
        __syncthreads();
        const bf16x8 af = *reinterpret_cast<const bf16x8*>(&Alds[wv * 16 + cc][g * 8]);
        #pragma unroll
        for (int nt = 0; nt < 4; ++nt) {
            const bf16x8 bfr = *reinterpret_cast<const bf16x8*>(&Blds[nt * 16 + cc][g * 8]);
            acc[nt] = __builtin_amdgcn_mfma_f32_16x16x32_bf16(af, bfr, acc[nt], 0, 0, 0);
        }
    }
    #pragma unroll
    for (int nt = 0; nt < 4; ++nt) {
        const int col = col0 + nt * 16 + cc;
        const float bv = bias[col];
        #pragma unroll
        for (int r = 0; r < 4; ++r) {
            const int row = R0 + wv * 16 + g * 4 + r;
            out[(size_t)row * 768 + col] = (u16)f2bf(acc[nt][r] + bv);
        }
    }
}

// ---------------------------------------------------------------------------
// Kernel 2: flash attention, swapped-operand MFMA.
//   grid (8 qc, 8 h, 16 ba); 4 waves; each wave: 2 q-sets x 16 q-rows (q=cc).
//   KVBLK=64.  S^T = mfma(A=K, B=Q)  ->  P lane-local  ->  O^T = mfma(A=V^T, B=P^T).
// ---------------------------------------------------------------------------
__global__ __launch_bounds__(256) void attn_kernel(const u16* __restrict__ QKV,
                                                   float* __restrict__ aout) {
    __shared__ u16 Klds[64][32];    // [key][d]
    __shared__ u16 Vlds[32][68];    // [d][key] transposed, pad 68 (8B-aligned rows)
    const int t = threadIdx.x;
    const int wv = t >> 6, lane = t & 63;
    const int g = lane >> 4, cc = lane & 15;
    const int qc = blockIdx.x;   // 0..7  (128 q rows per block)
    const int h  = blockIdx.y;   // 0..7
    const int ba = blockIdx.z;   // 0..15
    const float SCALE = 0.17677669529663687f * 1.44269504088896340736f; // rsqrt(32)*log2(e)
    const size_t base = (size_t)ba * 1024 * 768 + h * 96;

    // Q fragments (B-operand: col=q=cc, k=d=g*8+j), two q-sets
    bf16x8 qf[2];
    #pragma unroll
    for (int s = 0; s < 2; ++s) {
        const u16x8 qr = *reinterpret_cast<const u16x8*>(
            QKV + base + (size_t)(qc * 128 + s * 64 + wv * 16 + cc) * 768 + g * 8);
        #pragma unroll
        for (int j = 0; j < 8; ++j) qf[s][j] = f2bf(bf2f(qr[j]) * SCALE);
    }

    f32x4 o[2][2] = {};                      // [set][dhalf]: O^T[d=16*h'+4g+r][q=cc]
    float m[2] = {-3e38f, -3e38f}, l[2] = {0.f, 0.f};

    const int key_s = t >> 2;        // 0..63
    const int dp    = (t & 3) * 8;   // 0,8,16,24
    const u16* kgp = QKV + base + 32 + (size_t)key_s * 768 + dp;
    const u16* vgp = kgp + 32;

    u16x8 kpre = *reinterpret_cast<const u16x8*>(kgp);
    u16x8 vpre = *reinterpret_cast<const u16x8*>(vgp);

    for (int kt = 0; kt < 16; ++kt) {
        __syncthreads();
        *reinterpret_cast<u16x8*>(&Klds[key_s][dp]) = kpre;   // one b128 store
        #pragma unroll
        for (int i = 0; i < 8; ++i) Vlds[dp + i][key_s] = vpre[i];
        __syncthreads();
        if (kt < 15) {   // prefetch next tile into regs; latency hides under compute
            kpre = *reinterpret_cast<const u16x8*>(kgp + (size_t)(kt + 1) * 64 * 768);
            vpre = *reinterpret_cast<const u16x8*>(vgp + (size_t)(kt + 1) * 64 * 768);
        }

        // K A-fragments: row=key=cc (+16*t16), k=d=g*8+j
        bf16x8 kf[4];
        #pragma unroll
        for (int t16 = 0; t16 < 4; ++t16)
            kf[t16] = *reinterpret_cast<const bf16x8*>(&Klds[t16 * 16 + cc][g * 8]);
        // V^T A-fragments [dhalf][KG]: slot (g,j) -> key = KG*32 + (j>>2)*16 + 4g + (j&3)
        bf16x8 va[2][2];
        #pragma unroll
        for (int hh = 0; hh < 2; ++hh)
            #pragma unroll
            for (int kg = 0; kg < 2; ++kg) {
                const bf16x4 lo = *reinterpret_cast<const bf16x4*>(&Vlds[hh * 16 + cc][kg * 32 + 4 * g]);
                const bf16x4 hi = *reinterpret_cast<const bf16x4*>(&Vlds[hh * 16 + cc][kg * 32 + 16 + 4 * g]);
                va[hh][kg] = __builtin_shufflevector(lo, hi, 0, 1, 2, 3, 4, 5, 6, 7);
            }

        #pragma unroll
        for (int s = 0; s < 2; ++s) {
            const f32x4 z = {};
            f32x4 sc[4];
            #pragma unroll
            for (int t16 = 0; t16 < 4; ++t16)
                sc[t16] = __builtin_amdgcn_mfma_f32_16x16x32_bf16(kf[t16], qf[s], z, 0, 0, 0);

            // row max over 16 local + 2 shuffles (reduce over g)
            float mt = sc[0][0];
            #pragma unroll
            for (int t16 = 0; t16 < 4; ++t16)
                #pragma unroll
                for (int r = 0; r < 4; ++r) mt = fmaxf(mt, sc[t16][r]);
            mt = fmaxf(mt, __shfl_xor(mt, 16, 64));
            mt = fmaxf(mt, __shfl_xor(mt, 32, 64));
            const float mn = fmaxf(m[s], mt);
            const float fac = fexp2(m[s] - mn);
            m[s] = mn;

            float p[4][4];
            float rs = 0.f;
            #pragma unroll
            for (int t16 = 0; t16 < 4; ++t16)
                #pragma unroll
                for (int r = 0; r < 4; ++r) {
                    p[t16][r] = fexp2(sc[t16][r] - mn);
                    rs += p[t16][r];
                }
            rs += __shfl_xor(rs, 16, 64);
            rs += __shfl_xor(rs, 32, 64);
            l[s] = l[s] * fac + rs;
            o[s][0] *= fac;
            o[s][1] *= fac;

            // pack P -> bf16 B-fragments (lane-local; zero shuffles, zero LDS)
            union PW { int w[4]; bf16x8 v; } pb0, pb1;
            pb0.w[0] = (int)cvt_pk_bf16(p[0][0], p[0][1]);
            pb0.w[1] = (int)cvt_pk_bf16(p[0][2], p[0][3]);
            pb0.w[2] = (int)cvt_pk_bf16(p[1][0], p[1][1]);
            pb0.w[3] = (int)cvt_pk_bf16(p[1][2], p[1][3]);
            pb1.w[0] = (int)cvt_pk_bf16(p[2][0], p[2][1]);
            pb1.w[1] = (int)cvt_pk_bf16(p[2][2], p[2][3]);
            pb1.w[2] = (int)cvt_pk_bf16(p[3][0], p[3][1]);
            pb1.w[3] = (int)cvt_pk_bf16(p[3][2], p[3][3]);

            o[s][0] = __builtin_amdgcn_mfma_f32_16x16x32_bf16(va[0][0], pb0.v, o[s][0], 0, 0, 0);
            o[s][0] = __builtin_amdgcn_mfma_f32_16x16x32_bf16(va[0][1], pb1.v, o[s][0], 0, 0, 0);
            o[s][1] = __builtin_amdgcn_mfma_f32_16x16x32_bf16(va[1][0], pb0.v, o[s][1], 0, 0, 0);
            o[s][1] = __builtin_amdgcn_mfma_f32_16x16x32_bf16(va[1][1], pb1.v, o[s][1], 0, 0, 0);
        }
    }

    #pragma unroll
    for (int s = 0; s < 2; ++s) {
        const float inv = 1.f / l[s];
        const int q = qc * 128 + s * 64 + wv * 16 + cc;
        float* op = aout + (size_t)(ba * 1024 + q) * 256 + h * 32;
        f32x4 st0 = o[s][0] * inv;
        f32x4 st1 = o[s][1] * inv;
        *reinterpret_cast<f32x4*>(op + 4 * g)      = st0;   // d = 4g..4g+3
        *reinterpret_cast<f32x4*>(op + 16 + 4 * g) = st1;   // d = 16+4g..+3
    }
}

// ---------------------------------------------------------------------------
// Kernel 3: aout += dwconv7(V) + b_pe.  V channel c at QKV col (c>>5)*96+64+(c&31).
// ---------------------------------------------------------------------------
__global__ __launch_bounds__(256) void pe_add(const u16* __restrict__ QKV,
                                              const float* __restrict__ wpe,
                                              const float* __restrict__ bpe,
                                              float* __restrict__ aout) {
    const int c = threadIdx.x;
    const int R0 = blockIdx.x * 8;
    const int b = R0 >> 12;
    const int n0 = R0 & 4095;
    const int y = n0 >> 6, x0 = n0 & 63;
    const int col = (c >> 5) * 96 + 64 + (c & 31);
    const float bias = bpe[c];
    float w[49];
    #pragma unroll
    for (int i = 0; i < 49; ++i) w[i] = wpe[c * 49 + i];

    for (int p = 0; p < 8; ++p) {
        const int x = x0 + p;
        float acc = aout[(size_t)(R0 + p) * 256 + c] + bias;
        #pragma unroll
        for (int dy = 0; dy < 7; ++dy) {
            const int yy = y + dy - 3;
            if ((unsigned)yy < 64u) {
                #pragma unroll
                for (int dx = 0; dx < 7; ++dx) {
                    const int xx = x + dx - 3;
                    if ((unsigned)xx < 64u) {
                        acc += w[dy * 7 + dx] *
                               bf2f(QKV[(size_t)(b * 4096 + yy * 64 + xx) * 768 + col]);
                    }
                }
            }
        }
        aout[(size_t)(R0 + p) * 256 + c] = acc;
    }
}

// ---------------------------------------------------------------------------
// Kernel 4: proj GEMM.  out[b][c][n] = sum_k aout[R][k]*Wp[c][k] + bp[c]
// ---------------------------------------------------------------------------
__global__ __launch_bounds__(256) void proj_gemm(const float* __restrict__ A,
                                                 const float* __restrict__ W,
                                                 const float* __restrict__ bias,
                                                 float* __restrict__ out) {
    __shared__ union {
        struct { short A[64][40]; short B[64][40]; } s;
        float T[64][65];
    } u;
    const int t = threadIdx.x;
    const int wv = t >> 6, lane = t & 63;
    const int g = lane >> 4, cc = lane & 15;
    const int R0 = blockIdx.x * 64;
    const int b = R0 >> 12, n0 = R0 & 4095;
    const int col0 = blockIdx.y * 64;
    const int a_i  = t >> 2;
    const int a_kp = (t & 3) * 8;
    f32x4 acc[4] = {};

    for (int k0 = 0; k0 < 256; k0 += 32) {
        __syncthreads();
        {
            const float* ap = A + (size_t)(R0 + a_i) * 256 + k0 + a_kp;
            const float4 v0 = *reinterpret_cast<const float4*>(ap);
            const float4 v1 = *reinterpret_cast<const float4*>(ap + 4);
            bf16x8 pk;
            pk[0] = f2bf(v0.x); pk[1] = f2bf(v0.y); pk[2] = f2bf(v0.z); pk[3] = f2bf(v0.w);
            pk[4] = f2bf(v1.x); pk[5] = f2bf(v1.y); pk[6] = f2bf(v1.z); pk[7] = f2bf(v1.w);
            *reinterpret_cast<bf16x8*>(&u.s.A[a_i][a_kp]) = pk;

            const float* wp = W + (size_t)(col0 + a_i) * 256 + k0 + a_kp;
            const float4 w0 = *reinterpret_cast<const float4*>(wp);
            const float4 w1 = *reinterpret_cast<const float4*>(wp + 4);
            bf16x8 pw;
            pw[0] = f2bf(w0.x); pw[1] = f2bf(w0.y); pw[2] = f2bf(w0.z); pw[3] = f2bf(w0.w);
            pw[4] = f2bf(w1.x); pw[5] = f2bf(w1.y); pw[6] = f2bf(w1.z); pw[7] = f2bf(w1.w);
            *reinterpret_cast<bf16x8*>(&u.s.B[a_i][a_kp]) = pw;
        }
        __syncthreads();
        const bf16x8 af = *reinterpret_cast<const bf16x8*>(&u.s.A[wv * 16 + cc][g * 8]);
        #pragma unroll
        for (int nt = 0; nt < 4; ++nt) {
            const bf16x8 bfr = *reinterpret_cast<const bf16x8*>(&u.s.B[nt * 16 + cc][g * 8]);
            acc[nt] = __builtin_amdgcn_mfma_f32_16x16x32_bf16(af, bfr, acc[nt], 0, 0, 0);
        }
    }
    __syncthreads();
    #pragma unroll
    for (int nt = 0; nt < 4; ++nt) {
        const float bv = bias[col0 + nt * 16 + cc];
        #pragma unroll
        for (int r = 0; r < 4; ++r)
            u.T[nt * 16 + cc][wv * 16 + g * 4 + r] = acc[nt][r] + bv;
    }
    __syncthreads();
    #pragma unroll
    for (int it = 0; it < 16; ++it) {
        const int idx = it * 256 + t;
        const int ccc = idx >> 6, rr = idx & 63;
        out[(((size_t)(b * 256 + col0 + ccc)) << 12) + n0 + rr] = u.T[ccc][rr];
    }
}

// ---------------------------------------------------------------------------
extern "C" void kernel_launch(void* const* d_in, const int* in_sizes, int n_in,
                              void* d_out, int out_size, void* d_ws, size_t ws_size,
                              hipStream_t stream) {
    const float* x      = (const float*)d_in[0];
    const float* w_qkv  = (const float*)d_in[1];
    const float* b_qkv  = (const float*)d_in[2];
    const float* w_pe   = (const float*)d_in[3];
    const float* b_pe   = (const float*)d_in[4];
    const float* w_proj = (const float*)d_in[5];
    const float* b_proj = (const float*)d_in[6];
    float* out = (float*)d_out;

    u16*   qkvbuf = (u16*)d_ws;                              // bf16 [16384][768]
    float* aout   = (float*)((char*)d_ws + (size_t)16384 * 768 * 2);  // f32 [16384][256]

    qkv_gemm<<<dim3(256, 12), 256, 0, stream>>>(x, w_qkv, b_qkv, qkvbuf);
    attn_kernel<<<dim3(8, 8, 16), 256, 0, stream>>>(qkvbuf, aout);
    pe_add<<<2048, 256, 0, stream>>>(qkvbuf, w_pe, b_pe, aout);
    proj_gemm<<<dim3(256, 4), 256, 0, stream>>>(aout, w_proj, b_proj, out);
}

// Round 3
// 124.192 us; speedup vs baseline: 2.4492x; 1.6059x over previous
//
#include <hip/hip_runtime.h>
#include <hip/hip_bf16.h>

// ---------------------------------------------------------------------------
// AAttn (area attention) fused pipeline for MI355X (gfx950)
//  x:(4,256,64,64) -> qkv conv1x1 (bf16 out, + V in NCHW) -> attention
//  (16 areas x 8 heads, Na=1024, hd=32, swapped-operand MFMA flash)
//  -> pe_conv (dwconv7 on V, LDS plane tiling) -> proj conv1x1 (A = attn+pe)
// Workspace (64 MiB exactly):
//   QKV bf16 [16384][768]  25.17MB @ 0
//   AOUT f32 [16384][256]  16.78MB @ 25165824
//   VT   bf16 [1024][4096]  8.39MB @ 41943040   (b*256+c major)
//   PE   f32 [1024][4096]  16.78MB @ 50331648
// ---------------------------------------------------------------------------

typedef __attribute__((ext_vector_type(8))) short bf16x8;
typedef __attribute__((ext_vector_type(4))) short bf16x4;
typedef __attribute__((ext_vector_type(8))) unsigned short u16x8;
typedef __attribute__((ext_vector_type(4))) float f32x4;
typedef unsigned short u16;

__device__ __forceinline__ short f2bf(float f) {
    unsigned u = __builtin_bit_cast(unsigned, f);
    u = u + 0x7fffu + ((u >> 16) & 1u);   // RNE
    return (short)(u >> 16);
}
__device__ __forceinline__ float bf2f(u16 u) {
    return __builtin_bit_cast(float, (unsigned)u << 16);
}
__device__ __forceinline__ float fexp2(float x) {
#if __has_builtin(__builtin_amdgcn_exp2f)
    return __builtin_amdgcn_exp2f(x);
#else
    return exp2f(x);
#endif
}
__device__ __forceinline__ unsigned cvt_pk_bf16(float lo, float hi) {
    unsigned r;
    asm("v_cvt_pk_bf16_f32 %0, %1, %2" : "=v"(r) : "v"(lo), "v"(hi));
    return r;
}

// ---------------------------------------------------------------------------
// Kernel 1: QKV GEMM -> bf16 QKV buffer, plus V replicated to NCHW bf16 (Vt).
// ---------------------------------------------------------------------------
__global__ __launch_bounds__(256) void qkv_gemm(const float* __restrict__ X,
                                                const float* __restrict__ W,
                                                const float* __restrict__ bias,
                                                u16* __restrict__ out,
                                                u16* __restrict__ Vt) {
    __shared__ short Alds[64][40];
    __shared__ short Blds[64][40];
    const int t = threadIdx.x;
    const int wv = t >> 6, lane = t & 63;
    const int g = lane >> 4, cc = lane & 15;
    const int R0 = blockIdx.x * 64;
    const int b = R0 >> 12, n0 = R0 & 4095;
    const int col0 = blockIdx.y * 64;
    f32x4 acc[4] = {};

    const int a_kk = t >> 4;
    const int a_ii = (t & 15) * 4;
    const int b_col = t >> 2;
    const int b_kp  = (t & 3) * 8;

    for (int k0 = 0; k0 < 256; k0 += 32) {
        __syncthreads();
        #pragma unroll
        for (int it = 0; it < 2; ++it) {
            const int kk = a_kk + it * 16;
            const float4 v = *reinterpret_cast<const float4*>(
                X + (((size_t)(b * 256 + k0 + kk)) << 12) + n0 + a_ii);
            Alds[a_ii + 0][kk] = f2bf(v.x);
            Alds[a_ii + 1][kk] = f2bf(v.y);
            Alds[a_ii + 2][kk] = f2bf(v.z);
            Alds[a_ii + 3][kk] = f2bf(v.w);
        }
        {
            const float* wp = W + (size_t)(col0 + b_col) * 256 + k0 + b_kp;
            const float4 v0 = *reinterpret_cast<const float4*>(wp);
            const float4 v1 = *reinterpret_cast<const float4*>(wp + 4);
            bf16x8 pk;
            pk[0] = f2bf(v0.x); pk[1] = f2bf(v0.y); pk[2] = f2bf(v0.z); pk[3] = f2bf(v0.w);
            pk[4] = f2bf(v1.x); pk[5] = f2bf(v1.y); pk[6] = f2bf(v1.z); pk[7] = f2bf(v1.w);
            *reinterpret_cast<bf16x8*>(&Blds[b_col][b_kp]) = pk;
        }
        __syncthreads();
        const bf16x8 af = *reinterpret_cast<const bf16x8*>(&Alds[wv * 16 + cc][g * 8]);
        #pragma unroll
        for (int nt = 0; nt < 4; ++nt) {
            const bf16x8 bfr = *reinterpret_cast<const bf16x8*>(&Blds[nt * 16 + cc][g * 8]);
            acc[nt] = __builtin_amdgcn_mfma_f32_16x16x32_bf16(af, bfr, acc[nt], 0, 0, 0);
        }
    }
    #pragma unroll
    for (int nt = 0; nt < 4; ++nt) {
        const int col = col0 + nt * 16 + cc;
        const float bv = bias[col];
        const int m96 = col % 96;
        const bool isv = (m96 >= 64);
        const int vc = (col / 96) * 32 + (m96 - 64);
        #pragma unroll
        for (int r = 0; r < 4; ++r) {
            const int row = R0 + wv * 16 + g * 4 + r;
            const u16 val = (u16)f2bf(acc[nt][r] + bv);
            out[(size_t)row * 768 + col] = val;
            if (isv)
                Vt[(((size_t)(b * 256 + vc)) << 12) + (row & 4095)] = val;
        }
    }
}

// ---------------------------------------------------------------------------
// Kernel 2: flash attention, swapped-operand MFMA.
//   grid (4 qc, 8 h, 16 ba); 4 waves; each wave: 4 q-sets x 16 q-rows (q=cc).
//   KVBLK=64.  S^T = mfma(A=K, B=Q) -> P lane-local -> O^T = mfma(A=V^T, B=P^T).
// ---------------------------------------------------------------------------
__global__ __launch_bounds__(256) void attn_kernel(const u16* __restrict__ QKV,
                                                   float* __restrict__ aout) {
    __shared__ u16 Klds[64][32];
    __shared__ u16 Vlds[32][68];
    const int t = threadIdx.x;
    const int wv = t >> 6, lane = t & 63;
    const int g = lane >> 4, cc = lane & 15;
    const int qc = blockIdx.x;   // 0..3  (256 q rows per block)
    const int h  = blockIdx.y;   // 0..7
    const int ba = blockIdx.z;   // 0..15
    const float SCALE = 0.17677669529663687f * 1.44269504088896340736f;
    const size_t base = (size_t)ba * 1024 * 768 + h * 96;

    bf16x8 qf[4];
    #pragma unroll
    for (int s = 0; s < 4; ++s) {
        const u16x8 qr = *reinterpret_cast<const u16x8*>(
            QKV + base + (size_t)(qc * 256 + s * 64 + wv * 16 + cc) * 768 + g * 8);
        #pragma unroll
        for (int j = 0; j < 8; ++j) qf[s][j] = f2bf(bf2f(qr[j]) * SCALE);
    }

    f32x4 o[4][2] = {};
    float m[4] = {-3e38f, -3e38f, -3e38f, -3e38f};
    float l[4] = {0.f, 0.f, 0.f, 0.f};

    const int key_s = t >> 2;
    const int dp    = (t & 3) * 8;
    const u16* kgp = QKV + base + 32 + (size_t)key_s * 768 + dp;
    const u16* vgp = kgp + 32;

    u16x8 kpre = *reinterpret_cast<const u16x8*>(kgp);
    u16x8 vpre = *reinterpret_cast<const u16x8*>(vgp);

    for (int kt = 0; kt < 16; ++kt) {
        __syncthreads();
        *reinterpret_cast<u16x8*>(&Klds[key_s][dp]) = kpre;
        #pragma unroll
        for (int i = 0; i < 8; ++i) Vlds[dp + i][key_s] = vpre[i];
        __syncthreads();
        if (kt < 15) {
            kpre = *reinterpret_cast<const u16x8*>(kgp + (size_t)(kt + 1) * 64 * 768);
            vpre = *reinterpret_cast<const u16x8*>(vgp + (size_t)(kt + 1) * 64 * 768);
        }

        bf16x8 kf[4];
        #pragma unroll
        for (int t16 = 0; t16 < 4; ++t16)
            kf[t16] = *reinterpret_cast<const bf16x8*>(&Klds[t16 * 16 + cc][g * 8]);
        bf16x8 va[2][2];
        #pragma unroll
        for (int hh = 0; hh < 2; ++hh)
            #pragma unroll
            for (int kg = 0; kg < 2; ++kg) {
                const bf16x4 lo = *reinterpret_cast<const bf16x4*>(&Vlds[hh * 16 + cc][kg * 32 + 4 * g]);
                const bf16x4 hi = *reinterpret_cast<const bf16x4*>(&Vlds[hh * 16 + cc][kg * 32 + 16 + 4 * g]);
                va[hh][kg] = __builtin_shufflevector(lo, hi, 0, 1, 2, 3, 4, 5, 6, 7);
            }

        #pragma unroll
        for (int s = 0; s < 4; ++s) {
            const f32x4 z = {};
            f32x4 sc[4];
            #pragma unroll
            for (int t16 = 0; t16 < 4; ++t16)
                sc[t16] = __builtin_amdgcn_mfma_f32_16x16x32_bf16(kf[t16], qf[s], z, 0, 0, 0);

            float mt = sc[0][0];
            #pragma unroll
            for (int t16 = 0; t16 < 4; ++t16)
                #pragma unroll
                for (int r = 0; r < 4; ++r) mt = fmaxf(mt, sc[t16][r]);
            mt = fmaxf(mt, __shfl_xor(mt, 16, 64));
            mt = fmaxf(mt, __shfl_xor(mt, 32, 64));
            const float mn = fmaxf(m[s], mt);
            const float fac = fexp2(m[s] - mn);
            m[s] = mn;

            float p[4][4];
            float rs = 0.f;
            #pragma unroll
            for (int t16 = 0; t16 < 4; ++t16)
                #pragma unroll
                for (int r = 0; r < 4; ++r) {
                    p[t16][r] = fexp2(sc[t16][r] - mn);
                    rs += p[t16][r];
                }
            rs += __shfl_xor(rs, 16, 64);
            rs += __shfl_xor(rs, 32, 64);
            l[s] = l[s] * fac + rs;
            o[s][0] *= fac;
            o[s][1] *= fac;

            union PW { int w[4]; bf16x8 v; } pb0, pb1;
            pb0.w[0] = (int)cvt_pk_bf16(p[0][0], p[0][1]);
            pb0.w[1] = (int)cvt_pk_bf16(p[0][2], p[0][3]);
            pb0.w[2] = (int)cvt_pk_bf16(p[1][0], p[1][1]);
            pb0.w[3] = (int)cvt_pk_bf16(p[1][2], p[1][3]);
            pb1.w[0] = (int)cvt_pk_bf16(p[2][0], p[2][1]);
            pb1.w[1] = (int)cvt_pk_bf16(p[2][2], p[2][3]);
            pb1.w[2] = (int)cvt_pk_bf16(p[3][0], p[3][1]);
            pb1.w[3] = (int)cvt_pk_bf16(p[3][2], p[3][3]);

            o[s][0] = __builtin_amdgcn_mfma_f32_16x16x32_bf16(va[0][0], pb0.v, o[s][0], 0, 0, 0);
            o[s][0] = __builtin_amdgcn_mfma_f32_16x16x32_bf16(va[0][1], pb1.v, o[s][0], 0, 0, 0);
            o[s][1] = __builtin_amdgcn_mfma_f32_16x16x32_bf16(va[1][0], pb0.v, o[s][1], 0, 0, 0);
            o[s][1] = __builtin_amdgcn_mfma_f32_16x16x32_bf16(va[1][1], pb1.v, o[s][1], 0, 0, 0);
        }
    }

    #pragma unroll
    for (int s = 0; s < 4; ++s) {
        const float inv = 1.f / l[s];
        const int q = qc * 256 + s * 64 + wv * 16 + cc;
        float* op = aout + (size_t)(ba * 1024 + q) * 256 + h * 32;
        f32x4 st0 = o[s][0] * inv;
        f32x4 st1 = o[s][1] * inv;
        *reinterpret_cast<f32x4*>(op + 4 * g)      = st0;
        *reinterpret_cast<f32x4*>(op + 16 + 4 * g) = st1;
    }
}

// ---------------------------------------------------------------------------
// Kernel 3: pe_conv.  pebuf[b][c][n] = dwconv7(Vt plane) + b_pe[c].
// One block per (b,c) plane; LDS-staged f32 plane with zero halo; each thread
// computes 16 outputs via register sliding window.
// ---------------------------------------------------------------------------
__global__ __launch_bounds__(256) void pe_conv(const u16* __restrict__ Vt,
                                               const float* __restrict__ wpe,
                                               const float* __restrict__ bpe,
                                               float* __restrict__ pebuf) {
    __shared__ __align__(16) float P[70][76];
    const int t = threadIdx.x;
    const int bc = blockIdx.x;             // b*256 + c
    const int c = bc & 255;

    // zero whole tile (halo incl.)
    {
        f32x4 z = {};
        f32x4* p4 = reinterpret_cast<f32x4*>(&P[0][0]);
        #pragma unroll
        for (int i = 0; i < 6; ++i) {
            const int idx = t + i * 256;
            if (idx < 1330) p4[idx] = z;
        }
    }
    __syncthreads();
    // stage interior: row = t>>2 (0..63), 16 cols starting (t&3)*16
    {
        const int row = t >> 2, xo = (t & 3) * 16;
        const u16* src = Vt + (((size_t)bc) << 12) + row * 64 + xo;
        const u16x8 v0 = *reinterpret_cast<const u16x8*>(src);
        const u16x8 v1 = *reinterpret_cast<const u16x8*>(src + 8);
        #pragma unroll
        for (int j = 0; j < 8; ++j) {
            P[row + 3][xo + 3 + j]     = bf2f(v0[j]);
            P[row + 3][xo + 11 + j]    = bf2f(v1[j]);
        }
    }
    // weights (uniform across block -> scalar loads)
    float wk[49];
    #pragma unroll
    for (int i = 0; i < 49; ++i) wk[i] = wpe[c * 49 + i];
    const float bias = bpe[c];
    __syncthreads();

    const int y = t >> 2, x0 = (t & 3) * 16;
    float acc[16];
    #pragma unroll
    for (int j = 0; j < 16; ++j) acc[j] = bias;

    #pragma unroll
    for (int dy = 0; dy < 7; ++dy) {
        float win[24];
        #pragma unroll
        for (int w4 = 0; w4 < 6; ++w4)
            *reinterpret_cast<f32x4*>(&win[w4 * 4]) =
                *reinterpret_cast<const f32x4*>(&P[y + dy][x0 + w4 * 4]);
        #pragma unroll
        for (int dx = 0; dx < 7; ++dx) {
            const float wgt = wk[dy * 7 + dx];
            #pragma unroll
            for (int xx = 0; xx < 16; ++xx)
                acc[xx] = fmaf(wgt, win[xx + dx], acc[xx]);
        }
    }

    float* dst = pebuf + (((size_t)bc) << 12) + y * 64 + x0;
    #pragma unroll
    for (int w4 = 0; w4 < 4; ++w4)
        *reinterpret_cast<f32x4*>(dst + w4 * 4) =
            *reinterpret_cast<const f32x4*>(&acc[w4 * 4]);
}

// ---------------------------------------------------------------------------
// Kernel 4: proj GEMM.  A = aout[n][k] + pebuf[k][n]; out NCHW via LDS transpose.
// ---------------------------------------------------------------------------
__global__ __launch_bounds__(256) void proj_gemm(const float* __restrict__ A,
                                                 const float* __restrict__ PE,
                                                 const float* __restrict__ W,
                                                 const float* __restrict__ bias,
                                                 float* __restrict__ out) {
    __shared__ union {
        struct { short A[64][40]; short B[64][40]; } s;
        float T[64][65];
    } u;
    const int t = threadIdx.x;
    const int wv = t >> 6, lane = t & 63;
    const int g = lane >> 4, cc = lane & 15;
    const int R0 = blockIdx.x * 64;
    const int b = R0 >> 12, n0 = R0 & 4095;
    const int col0 = blockIdx.y * 64;
    const int a_i  = t >> 2;
    const int a_kp = (t & 3) * 8;
    f32x4 acc[4] = {};

    for (int k0 = 0; k0 < 256; k0 += 32) {
        __syncthreads();
        {
            const float* ap = A + (size_t)(R0 + a_i) * 256 + k0 + a_kp;
            const float4 v0 = *reinterpret_cast<const float4*>(ap);
            const float4 v1 = *reinterpret_cast<const float4*>(ap + 4);
            const float* pp = PE + (((size_t)(b * 256 + k0 + a_kp)) << 12) + n0 + a_i;
            bf16x8 pk;
            pk[0] = f2bf(v0.x + pp[0]);
            pk[1] = f2bf(v0.y + pp[(size_t)1 << 12]);
            pk[2] = f2bf(v0.z + pp[(size_t)2 << 12]);
            pk[3] = f2bf(v0.w + pp[(size_t)3 << 12]);
            pk[4] = f2bf(v1.x + pp[(size_t)4 << 12]);
            pk[5] = f2bf(v1.y + pp[(size_t)5 << 12]);
            pk[6] = f2bf(v1.z + pp[(size_t)6 << 12]);
            pk[7] = f2bf(v1.w + pp[(size_t)7 << 12]);
            *reinterpret_cast<bf16x8*>(&u.s.A[a_i][a_kp]) = pk;

            const float* wp = W + (size_t)(col0 + a_i) * 256 + k0 + a_kp;
            const float4 w0 = *reinterpret_cast<const float4*>(wp);
            const float4 w1 = *reinterpret_cast<const float4*>(wp + 4);
            bf16x8 pw;
            pw[0] = f2bf(w0.x); pw[1] = f2bf(w0.y); pw[2] = f2bf(w0.z); pw[3] = f2bf(w0.w);
            pw[4] = f2bf(w1.x); pw[5] = f2bf(w1.y); pw[6] = f2bf(w1.z); pw[7] = f2bf(w1.w);
            *reinterpret_cast<bf16x8*>(&u.s.B[a_i][a_kp]) = pw;
        }
        __syncthreads();
        const bf16x8 af = *reinterpret_cast<const bf16x8*>(&u.s.A[wv * 16 + cc][g * 8]);
        #pragma unroll
        for (int nt = 0; nt < 4; ++nt) {
            const bf16x8 bfr = *reinterpret_cast<const bf16x8*>(&u.s.B[nt * 16 + cc][g * 8]);
            acc[nt] = __builtin_amdgcn_mfma_f32_16x16x32_bf16(af, bfr, acc[nt], 0, 0, 0);
        }
    }
    __syncthreads();
    #pragma unroll
    for (int nt = 0; nt < 4; ++nt) {
        const float bv = bias[col0 + nt * 16 + cc];
        #pragma unroll
        for (int r = 0; r < 4; ++r)
            u.T[nt * 16 + cc][wv * 16 + g * 4 + r] = acc[nt][r] + bv;
    }
    __syncthreads();
    #pragma unroll
    for (int it = 0; it < 16; ++it) {
        const int idx = it * 256 + t;
        const int ccc = idx >> 6, rr = idx & 63;
        out[(((size_t)(b * 256 + col0 + ccc)) << 12) + n0 + rr] = u.T[ccc][rr];
    }
}

// ---------------------------------------------------------------------------
extern "C" void kernel_launch(void* const* d_in, const int* in_sizes, int n_in,
                              void* d_out, int out_size, void* d_ws, size_t ws_size,
                              hipStream_t stream) {
    const float* x      = (const float*)d_in[0];
    const float* w_qkv  = (const float*)d_in[1];
    const float* b_qkv  = (const float*)d_in[2];
    const float* w_pe   = (const float*)d_in[3];
    const float* b_pe   = (const float*)d_in[4];
    const float* w_proj = (const float*)d_in[5];
    const float* b_proj = (const float*)d_in[6];
    float* out = (float*)d_out;

    char* ws = (char*)d_ws;
    u16*   qkvbuf = (u16*)ws;                                  // 25,165,824 B
    float* aout   = (float*)(ws + 25165824);                   // 16,777,216 B
    u16*   vt     = (u16*)(ws + 41943040);                     //  8,388,608 B
    float* pebuf  = (float*)(ws + 50331648);                   // 16,777,216 B

    qkv_gemm<<<dim3(256, 12), 256, 0, stream>>>(x, w_qkv, b_qkv, qkvbuf, vt);
    attn_kernel<<<dim3(4, 8, 16), 256, 0, stream>>>(qkvbuf, aout);
    pe_conv<<<1024, 256, 0, stream>>>(vt, w_pe, b_pe, pebuf);
    proj_gemm<<<dim3(256, 4), 256, 0, stream>>>(aout, pebuf, w_proj, b_proj, out);
}

// Round 6
// 120.356 us; speedup vs baseline: 2.5273x; 1.0319x over previous
//
#include <hip/hip_runtime.h>
#include <hip/hip_bf16.h>

// ---------------------------------------------------------------------------
// AAttn (area attention) fused pipeline for MI355X (gfx950)
//  x:(4,256,64,64) -> qkv conv1x1 (bf16 out, + V in NCHW) -> attention
//  (16 areas x 8 heads, Na=1024, hd=32, swapped-operand MFMA flash, online
//  max) -> pe_conv (dwconv7 on V) -> proj conv1x1 (A = attn+pe)
// Workspace (64 MiB exactly):
//   QKV bf16 [16384][768]  25.17MB @ 0
//   AOUT f32 [16384][256]  16.78MB @ 25165824
//   VT   bf16 [1024][4096]  8.39MB @ 41943040   (b*256+c major)
//   PE   f32 [1024][4096]  16.78MB @ 50331648
// ---------------------------------------------------------------------------

typedef __attribute__((ext_vector_type(8))) short bf16x8;
typedef __attribute__((ext_vector_type(4))) short bf16x4;
typedef __attribute__((ext_vector_type(8))) unsigned short u16x8;
typedef __attribute__((ext_vector_type(4))) float f32x4;
typedef unsigned short u16;

__device__ __forceinline__ short f2bf(float f) {
    unsigned u = __builtin_bit_cast(unsigned, f);
    u = u + 0x7fffu + ((u >> 16) & 1u);   // RNE
    return (short)(u >> 16);
}
__device__ __forceinline__ float bf2f(u16 u) {
    return __builtin_bit_cast(float, (unsigned)u << 16);
}
__device__ __forceinline__ float fexp2(float x) {
#if __has_builtin(__builtin_amdgcn_exp2f)
    return __builtin_amdgcn_exp2f(x);
#else
    return exp2f(x);
#endif
}
__device__ __forceinline__ unsigned cvt_pk_bf16(float lo, float hi) {
    unsigned r;
    asm("v_cvt_pk_bf16_f32 %0, %1, %2" : "=v"(r) : "v"(lo), "v"(hi));
    return r;
}

// ---------------------------------------------------------------------------
// Kernel 1: QKV GEMM -> bf16 QKV buffer, plus V replicated to NCHW bf16 (Vt).
// (round-3 known-good version)
// ---------------------------------------------------------------------------
__global__ __launch_bounds__(256) void qkv_gemm(const float* __restrict__ X,
                                                const float* __restrict__ W,
                                                const float* __restrict__ bias,
                                                u16* __restrict__ out,
                                                u16* __restrict__ Vt) {
    __shared__ short Alds[64][40];
    __shared__ short Blds[64][40];
    const int t = threadIdx.x;
    const int wv = t >> 6, lane = t & 63;
    const int g = lane >> 4, cc = lane & 15;
    const int R0 = blockIdx.x * 64;
    const int b = R0 >> 12, n0 = R0 & 4095;
    const int col0 = blockIdx.y * 64;
    f32x4 acc[4] = {};

    const int a_kk = t >> 4;
    const int a_ii = (t & 15) * 4;
    const int b_col = t >> 2;
    const int b_kp  = (t & 3) * 8;

    for (int k0 = 0; k0 < 256; k0 += 32) {
        __syncthreads();
        #pragma unroll
        for (int it = 0; it < 2; ++it) {
            const int kk = a_kk + it * 16;
            const float4 v = *reinterpret_cast<const float4*>(
                X + (((size_t)(b * 256 + k0 + kk)) << 12) + n0 + a_ii);
            Alds[a_ii + 0][kk] = f2bf(v.x);
            Alds[a_ii + 1][kk] = f2bf(v.y);
            Alds[a_ii + 2][kk] = f2bf(v.z);
            Alds[a_ii + 3][kk] = f2bf(v.w);
        }
        {
            const float* wp = W + (size_t)(col0 + b_col) * 256 + k0 + b_kp;
            const float4 v0 = *reinterpret_cast<const float4*>(wp);
            const float4 v1 = *reinterpret_cast<const float4*>(wp + 4);
            bf16x8 pk;
            pk[0] = f2bf(v0.x); pk[1] = f2bf(v0.y); pk[2] = f2bf(v0.z); pk[3] = f2bf(v0.w);
            pk[4] = f2bf(v1.x); pk[5] = f2bf(v1.y); pk[6] = f2bf(v1.z); pk[7] = f2bf(v1.w);
            *reinterpret_cast<bf16x8*>(&Blds[b_col][b_kp]) = pk;
        }
        __syncthreads();
        const bf16x8 af = *reinterpret_cast<const bf16x8*>(&Alds[wv * 16 + cc][g * 8]);
        #pragma unroll
        for (int nt = 0; nt < 4; ++nt) {
            const bf16x8 bfr = *reinterpret_cast<const bf16x8*>(&Blds[nt * 16 + cc][g * 8]);
            acc[nt] = __builtin_amdgcn_mfma_f32_16x16x32_bf16(af, bfr, acc[nt], 0, 0, 0);
        }
    }
    #pragma unroll
    for (int nt = 0; nt < 4; ++nt) {
        const int col = col0 + nt * 16 + cc;
        const float bv = bias[col];
        const int m96 = col % 96;
        const bool isv = (m96 >= 64);
        const int vc = (col / 96) * 32 + (m96 - 64);
        #pragma unroll
        for (int r = 0; r < 4; ++r) {
            const int row = R0 + wv * 16 + g * 4 + r;
            const u16 val = (u16)f2bf(acc[nt][r] + bv);
            out[(size_t)row * 768 + col] = val;
            if (isv)
                Vt[(((size_t)(b * 256 + vc)) << 12) + (row & 4095)] = val;
        }
    }
}

// ---------------------------------------------------------------------------
// Kernel 2: flash attention, swapped-operand MFMA.  (round-2 text, verbatim:
// online-max softmax, single LDS buffer, two barriers/tile, qc=8 x 2 q-sets.)
//   grid (8 qc, 8 h, 16 ba); 4 waves; each wave: 2 q-sets x 16 q rows (q=cc).
//   KVBLK=64.  S^T = mfma(A=K, B=Q) -> P lane-local -> O^T = mfma(A=V^T, B=P^T).
// ---------------------------------------------------------------------------
__global__ __launch_bounds__(256) void attn_kernel(const u16* __restrict__ QKV,
                                                   float* __restrict__ aout) {
    __shared__ u16 Klds[64][32];
    __shared__ u16 Vlds[32][68];
    const int t = threadIdx.x;
    const int wv = t >> 6, lane = t & 63;
    const int g = lane >> 4, cc = lane & 15;
    const int qc = blockIdx.x;   // 0..7  (128 q rows per block)
    const int h  = blockIdx.y;   // 0..7
    const int ba = blockIdx.z;   // 0..15
    const float SCALE = 0.17677669529663687f * 1.44269504088896340736f;
    const size_t base = (size_t)ba * 1024 * 768 + h * 96;

    bf16x8 qf[2];
    #pragma unroll
    for (int s = 0; s < 2; ++s) {
        const u16x8 qr = *reinterpret_cast<const u16x8*>(
            QKV + base + (size_t)(qc * 128 + s * 64 + wv * 16 + cc) * 768 + g * 8);
        #pragma unroll
        for (int j = 0; j < 8; ++j) qf[s][j] = f2bf(bf2f(qr[j]) * SCALE);
    }

    f32x4 o[2][2] = {};
    float m[2] = {-3e38f, -3e38f}, l[2] = {0.f, 0.f};

    const int key_s = t >> 2;
    const int dp    = (t & 3) * 8;
    const u16* kgp = QKV + base + 32 + (size_t)key_s * 768 + dp;
    const u16* vgp = kgp + 32;

    u16x8 kpre = *reinterpret_cast<const u16x8*>(kgp);
    u16x8 vpre = *reinterpret_cast<const u16x8*>(vgp);

    for (int kt = 0; kt < 16; ++kt) {
        __syncthreads();
        *reinterpret_cast<u16x8*>(&Klds[key_s][dp]) = kpre;
        #pragma unroll
        for (int i = 0; i < 8; ++i) Vlds[dp + i][key_s] = vpre[i];
        __syncthreads();
        if (kt < 15) {   // prefetch next tile into regs
            kpre = *reinterpret_cast<const u16x8*>(kgp + (size_t)(kt + 1) * 64 * 768);
            vpre = *reinterpret_cast<const u16x8*>(vgp + (size_t)(kt + 1) * 64 * 768);
        }

        bf16x8 kf[4];
        #pragma unroll
        for (int t16 = 0; t16 < 4; ++t16)
            kf[t16] = *reinterpret_cast<const bf16x8*>(&Klds[t16 * 16 + cc][g * 8]);
        bf16x8 va[2][2];
        #pragma unroll
        for (int hh = 0; hh < 2; ++hh)
            #pragma unroll
            for (int kg = 0; kg < 2; ++kg) {
                const bf16x4 lo = *reinterpret_cast<const bf16x4*>(&Vlds[hh * 16 + cc][kg * 32 + 4 * g]);
                const bf16x4 hi = *reinterpret_cast<const bf16x4*>(&Vlds[hh * 16 + cc][kg * 32 + 16 + 4 * g]);
                va[hh][kg] = __builtin_shufflevector(lo, hi, 0, 1, 2, 3, 4, 5, 6, 7);
            }

        #pragma unroll
        for (int s = 0; s < 2; ++s) {
            const f32x4 z = {};
            f32x4 sc[4];
            #pragma unroll
            for (int t16 = 0; t16 < 4; ++t16)
                sc[t16] = __builtin_amdgcn_mfma_f32_16x16x32_bf16(kf[t16], qf[s], z, 0, 0, 0);

            float mt = sc[0][0];
            #pragma unroll
            for (int t16 = 0; t16 < 4; ++t16)
                #pragma unroll
                for (int r = 0; r < 4; ++r) mt = fmaxf(mt, sc[t16][r]);
            mt = fmaxf(mt, __shfl_xor(mt, 16, 64));
            mt = fmaxf(mt, __shfl_xor(mt, 32, 64));
            const float mn = fmaxf(m[s], mt);
            const float fac = fexp2(m[s] - mn);
            m[s] = mn;

            float p[4][4];
            float rs = 0.f;
            #pragma unroll
            for (int t16 = 0; t16 < 4; ++t16)
                #pragma unroll
                for (int r = 0; r < 4; ++r) {
                    p[t16][r] = fexp2(sc[t16][r] - mn);
                    rs += p[t16][r];
                }
            rs += __shfl_xor(rs, 16, 64);
            rs += __shfl_xor(rs, 32, 64);
            l[s] = l[s] * fac + rs;
            o[s][0] *= fac;
            o[s][1] *= fac;

            union PW { int w[4]; bf16x8 v; } pb0, pb1;
            pb0.w[0] = (int)cvt_pk_bf16(p[0][0], p[0][1]);
            pb0.w[1] = (int)cvt_pk_bf16(p[0][2], p[0][3]);
            pb0.w[2] = (int)cvt_pk_bf16(p[1][0], p[1][1]);
            pb0.w[3] = (int)cvt_pk_bf16(p[1][2], p[1][3]);
            pb1.w[0] = (int)cvt_pk_bf16(p[2][0], p[2][1]);
            pb1.w[1] = (int)cvt_pk_bf16(p[2][2], p[2][3]);
            pb1.w[2] = (int)cvt_pk_bf16(p[3][0], p[3][1]);
            pb1.w[3] = (int)cvt_pk_bf16(p[3][2], p[3][3]);

            o[s][0] = __builtin_amdgcn_mfma_f32_16x16x32_bf16(va[0][0], pb0.v, o[s][0], 0, 0, 0);
            o[s][0] = __builtin_amdgcn_mfma_f32_16x16x32_bf16(va[0][1], pb1.v, o[s][0], 0, 0, 0);
            o[s][1] = __builtin_amdgcn_mfma_f32_16x16x32_bf16(va[1][0], pb0.v, o[s][1], 0, 0, 0);
            o[s][1] = __builtin_amdgcn_mfma_f32_16x16x32_bf16(va[1][1], pb1.v, o[s][1], 0, 0, 0);
        }
    }

    #pragma unroll
    for (int s = 0; s < 2; ++s) {
        const float inv = 1.f / l[s];
        const int q = qc * 128 + s * 64 + wv * 16 + cc;
        float* op = aout + (size_t)(ba * 1024 + q) * 256 + h * 32;
        f32x4 st0 = o[s][0] * inv;
        f32x4 st1 = o[s][1] * inv;
        *reinterpret_cast<f32x4*>(op + 4 * g)      = st0;
        *reinterpret_cast<f32x4*>(op + 16 + 4 * g) = st1;
    }
}

// ---------------------------------------------------------------------------
// Kernel 3: pe_conv.  pebuf[b][c][n] = dwconv7(Vt plane) + b_pe[c].
// ---------------------------------------------------------------------------
__global__ __launch_bounds__(256) void pe_conv(const u16* __restrict__ Vt,
                                               const float* __restrict__ wpe,
                                               const float* __restrict__ bpe,
                                               float* __restrict__ pebuf) {
    __shared__ __align__(16) float P[70][76];
    const int t = threadIdx.x;
    const int bc = blockIdx.x;             // b*256 + c
    const int c = bc & 255;

    {
        f32x4 z = {};
        f32x4* p4 = reinterpret_cast<f32x4*>(&P[0][0]);
        #pragma unroll
        for (int i = 0; i < 6; ++i) {
            const int idx = t + i * 256;
            if (idx < 1330) p4[idx] = z;
        }
    }
    __syncthreads();
    {
        const int row = t >> 2, xo = (t & 3) * 16;
        const u16* src = Vt + (((size_t)bc) << 12) + row * 64 + xo;
        const u16x8 v0 = *reinterpret_cast<const u16x8*>(src);
        const u16x8 v1 = *reinterpret_cast<const u16x8*>(src + 8);
        #pragma unroll
        for (int j = 0; j < 8; ++j) {
            P[row + 3][xo + 3 + j]  = bf2f(v0[j]);
            P[row + 3][xo + 11 + j] = bf2f(v1[j]);
        }
    }
    float wk[49];
    #pragma unroll
    for (int i = 0; i < 49; ++i) wk[i] = wpe[c * 49 + i];
    const float bias = bpe[c];
    __syncthreads();

    const int y = t >> 2, x0 = (t & 3) * 16;
    float acc[16];
    #pragma unroll
    for (int j = 0; j < 16; ++j) acc[j] = bias;

    #pragma unroll
    for (int dy = 0; dy < 7; ++dy) {
        float win[24];
        #pragma unroll
        for (int w4 = 0; w4 < 6; ++w4)
            *reinterpret_cast<f32x4*>(&win[w4 * 4]) =
                *reinterpret_cast<const f32x4*>(&P[y + dy][x0 + w4 * 4]);
        #pragma unroll
        for (int dx = 0; dx < 7; ++dx) {
            const float wgt = wk[dy * 7 + dx];
            #pragma unroll
            for (int xx = 0; xx < 16; ++xx)
                acc[xx] = fmaf(wgt, win[xx + dx], acc[xx]);
        }
    }

    float* dst = pebuf + (((size_t)bc) << 12) + y * 64 + x0;
    #pragma unroll
    for (int w4 = 0; w4 < 4; ++w4)
        *reinterpret_cast<f32x4*>(dst + w4 * 4) =
            *reinterpret_cast<const f32x4*>(&acc[w4 * 4]);
}

// ---------------------------------------------------------------------------
// Kernel 4: proj GEMM.  A = aout[n][k] + pebuf[k][n]; out NCHW via LDS transpose.
// ---------------------------------------------------------------------------
__global__ __launch_bounds__(256) void proj_gemm(const float* __restrict__ A,
                                                 const float* __restrict__ PE,
                                                 const float* __restrict__ W,
                                                 const float* __restrict__ bias,
                                                 float* __restrict__ out) {
    __shared__ union {
        struct { short A[64][40]; short B[64][40]; } s;
        float T[64][65];
    } u;
    const int t = threadIdx.x;
    const int wv = t >> 6, lane = t & 63;
    const int g = lane >> 4, cc = lane & 15;
    const int R0 = blockIdx.x * 64;
    const int b = R0 >> 12, n0 = R0 & 4095;
    const int col0 = blockIdx.y * 64;
    const int a_i  = t >> 2;
    const int a_kp = (t & 3) * 8;
    f32x4 acc[4] = {};

    for (int k0 = 0; k0 < 256; k0 += 32) {
        __syncthreads();
        {
            const float* ap = A + (size_t)(R0 + a_i) * 256 + k0 + a_kp;
            const float4 v0 = *reinterpret_cast<const float4*>(ap);
            const float4 v1 = *reinterpret_cast<const float4*>(ap + 4);
            const float* pp = PE + (((size_t)(b * 256 + k0 + a_kp)) << 12) + n0 + a_i;
            bf16x8 pk;
            pk[0] = f2bf(v0.x + pp[0]);
            pk[1] = f2bf(v0.y + pp[(size_t)1 << 12]);
            pk[2] = f2bf(v0.z + pp[(size_t)2 << 12]);
            pk[3] = f2bf(v0.w + pp[(size_t)3 << 12]);
            pk[4] = f2bf(v1.x + pp[(size_t)4 << 12]);
            pk[5] = f2bf(v1.y + pp[(size_t)5 << 12]);
            pk[6] = f2bf(v1.z + pp[(size_t)6 << 12]);
            pk[7] = f2bf(v1.w + pp[(size_t)7 << 12]);
            *reinterpret_cast<bf16x8*>(&u.s.A[a_i][a_kp]) = pk;

            const float* wp = W + (size_t)(col0 + a_i) * 256 + k0 + a_kp;
            const float4 w0 = *reinterpret_cast<const float4*>(wp);
            const float4 w1 = *reinterpret_cast<const float4*>(wp + 4);
            bf16x8 pw;
            pw[0] = f2bf(w0.x); pw[1] = f2bf(w0.y); pw[2] = f2bf(w0.z); pw[3] = f2bf(w0.w);
            pw[4] = f2bf(w1.x); pw[5] = f2bf(w1.y); pw[6] = f2bf(w1.z); pw[7] = f2bf(w1.w);
            *reinterpret_cast<bf16x8*>(&u.s.B[a_i][a_kp]) = pw;
        }
        __syncthreads();
        const bf16x8 af = *reinterpret_cast<const bf16x8*>(&u.s.A[wv * 16 + cc][g * 8]);
        #pragma unroll
        for (int nt = 0; nt < 4; ++nt) {
            const bf16x8 bfr = *reinterpret_cast<const bf16x8*>(&u.s.B[nt * 16 + cc][g * 8]);
            acc[nt] = __builtin_amdgcn_mfma_f32_16x16x32_bf16(af, bfr, acc[nt], 0, 0, 0);
        }
    }
    __syncthreads();
    #pragma unroll
    for (int nt = 0; nt < 4; ++nt) {
        const float bv = bias[col0 + nt * 16 + cc];
        #pragma unroll
        for (int r = 0; r < 4; ++r)
            u.T[nt * 16 + cc][wv * 16 + g * 4 + r] = acc[nt][r] + bv;
    }
    __syncthreads();
    #pragma unroll
    for (int it = 0; it < 16; ++it) {
        const int idx = it * 256 + t;
        const int ccc = idx >> 6, rr = idx & 63;
        out[(((size_t)(b * 256 + col0 + ccc)) << 12) + n0 + rr] = u.T[ccc][rr];
    }
}

// ---------------------------------------------------------------------------
extern "C" void kernel_launch(void* const* d_in, const int* in_sizes, int n_in,
                              void* d_out, int out_size, void* d_ws, size_t ws_size,
                              hipStream_t stream) {
    const float* x      = (const float*)d_in[0];
    const float* w_qkv  = (const float*)d_in[1];
    const float* b_qkv  = (const float*)d_in[2];
    const float* w_pe   = (const float*)d_in[3];
    const float* b_pe   = (const float*)d_in[4];
    const float* w_proj = (const float*)d_in[5];
    const float* b_proj = (const float*)d_in[6];
    float* out = (float*)d_out;

    char* ws = (char*)d_ws;
    u16*   qkvbuf = (u16*)ws;                                  // 25,165,824 B
    float* aout   = (float*)(ws + 25165824);                   // 16,777,216 B
    u16*   vt     = (u16*)(ws + 41943040);                     //  8,388,608 B
    float* pebuf  = (float*)(ws + 50331648);                   // 16,777,216 B

    qkv_gemm<<<dim3(256, 12), 256, 0, stream>>>(x, w_qkv, b_qkv, qkvbuf, vt);
    attn_kernel<<<dim3(8, 8, 16), 256, 0, stream>>>(qkvbuf, aout);
    pe_conv<<<1024, 256, 0, stream>>>(vt, w_pe, b_pe, pebuf);
    proj_gemm<<<dim3(256, 4), 256, 0, stream>>>(aout, pebuf, w_proj, b_proj, out);
}

// Round 7
// 118.816 us; speedup vs baseline: 2.5600x; 1.0130x over previous
//
#include <hip/hip_runtime.h>
#include <hip/hip_bf16.h>

// ---------------------------------------------------------------------------
// AAttn (area attention) fused pipeline for MI355X (gfx950)
//  x:(4,256,64,64) -> qkv conv1x1 (bf16 out, + V in NCHW) -> attention
//  (16 areas x 8 heads, Na=1024, hd=32, swapped-operand MFMA flash, online
//  max) -> pe_conv (dwconv7 on V) -> proj conv1x1 (A = attn+pe)
// Workspace (64 MiB exactly):
//   QKV bf16 [16384][768]  25.17MB @ 0
//   AOUT f32 [16384][256]  16.78MB @ 25165824
//   VT   bf16 [1024][4096]  8.39MB @ 41943040   (b*256+c major)
//   PE   f32 [1024][4096]  16.78MB @ 50331648
// ---------------------------------------------------------------------------

typedef __attribute__((ext_vector_type(8))) short bf16x8;
typedef __attribute__((ext_vector_type(4))) short bf16x4;
typedef __attribute__((ext_vector_type(8))) unsigned short u16x8;
typedef __attribute__((ext_vector_type(4))) float f32x4;
typedef unsigned short u16;

__device__ __forceinline__ short f2bf(float f) {
    unsigned u = __builtin_bit_cast(unsigned, f);
    u = u + 0x7fffu + ((u >> 16) & 1u);   // RNE
    return (short)(u >> 16);
}
__device__ __forceinline__ float bf2f(u16 u) {
    return __builtin_bit_cast(float, (unsigned)u << 16);
}
__device__ __forceinline__ float fexp2(float x) {
#if __has_builtin(__builtin_amdgcn_exp2f)
    return __builtin_amdgcn_exp2f(x);
#else
    return exp2f(x);
#endif
}
__device__ __forceinline__ unsigned cvt_pk_bf16(float lo, float hi) {
    unsigned r;
    asm("v_cvt_pk_bf16_f32 %0, %1, %2" : "=v"(r) : "v"(lo), "v"(hi));
    return r;
}

// ---------------------------------------------------------------------------
// Kernel 1: QKV GEMM -> bf16 QKV buffer, plus V replicated to NCHW bf16 (Vt).
// (round-3 known-good version)
// ---------------------------------------------------------------------------
__global__ __launch_bounds__(256) void qkv_gemm(const float* __restrict__ X,
                                                const float* __restrict__ W,
                                                const float* __restrict__ bias,
                                                u16* __restrict__ out,
                                                u16* __restrict__ Vt) {
    __shared__ short Alds[64][40];
    __shared__ short Blds[64][40];
    const int t = threadIdx.x;
    const int wv = t >> 6, lane = t & 63;
    const int g = lane >> 4, cc = lane & 15;
    const int R0 = blockIdx.x * 64;
    const int b = R0 >> 12, n0 = R0 & 4095;
    const int col0 = blockIdx.y * 64;
    f32x4 acc[4] = {};

    const int a_kk = t >> 4;
    const int a_ii = (t & 15) * 4;
    const int b_col = t >> 2;
    const int b_kp  = (t & 3) * 8;

    for (int k0 = 0; k0 < 256; k0 += 32) {
        __syncthreads();
        #pragma unroll
        for (int it = 0; it < 2; ++it) {
            const int kk = a_kk + it * 16;
            const float4 v = *reinterpret_cast<const float4*>(
                X + (((size_t)(b * 256 + k0 + kk)) << 12) + n0 + a_ii);
            Alds[a_ii + 0][kk] = f2bf(v.x);
            Alds[a_ii + 1][kk] = f2bf(v.y);
            Alds[a_ii + 2][kk] = f2bf(v.z);
            Alds[a_ii + 3][kk] = f2bf(v.w);
        }
        {
            const float* wp = W + (size_t)(col0 + b_col) * 256 + k0 + b_kp;
            const float4 v0 = *reinterpret_cast<const float4*>(wp);
            const float4 v1 = *reinterpret_cast<const float4*>(wp + 4);
            bf16x8 pk;
            pk[0] = f2bf(v0.x); pk[1] = f2bf(v0.y); pk[2] = f2bf(v0.z); pk[3] = f2bf(v0.w);
            pk[4] = f2bf(v1.x); pk[5] = f2bf(v1.y); pk[6] = f2bf(v1.z); pk[7] = f2bf(v1.w);
            *reinterpret_cast<bf16x8*>(&Blds[b_col][b_kp]) = pk;
        }
        __syncthreads();
        const bf16x8 af = *reinterpret_cast<const bf16x8*>(&Alds[wv * 16 + cc][g * 8]);
        #pragma unroll
        for (int nt = 0; nt < 4; ++nt) {
            const bf16x8 bfr = *reinterpret_cast<const bf16x8*>(&Blds[nt * 16 + cc][g * 8]);
            acc[nt] = __builtin_amdgcn_mfma_f32_16x16x32_bf16(af, bfr, acc[nt], 0, 0, 0);
        }
    }
    #pragma unroll
    for (int nt = 0; nt < 4; ++nt) {
        const int col = col0 + nt * 16 + cc;
        const float bv = bias[col];
        const int m96 = col % 96;
        const bool isv = (m96 >= 64);
        const int vc = (col / 96) * 32 + (m96 - 64);
        #pragma unroll
        for (int r = 0; r < 4; ++r) {
            const int row = R0 + wv * 16 + g * 4 + r;
            const u16 val = (u16)f2bf(acc[nt][r] + bv);
            out[(size_t)row * 768 + col] = val;
            if (isv)
                Vt[(((size_t)(b * 256 + vc)) << 12) + (row & 4095)] = val;
        }
    }
}

// ---------------------------------------------------------------------------
// Kernel 2: flash attention, swapped-operand MFMA.  (round-2/6 text; ONLY
// change: blockIdx.x <-> blockIdx.y roles so the 8 qc-blocks sharing a
// (ba,h) K/V panel have linear ids congruent mod 8 -> same XCD L2.)
//   grid (8 h, 8 qc, 16 ba); 4 waves; each wave: 2 q-sets x 16 q rows (q=cc).
//   KVBLK=64.  S^T = mfma(A=K, B=Q) -> P lane-local -> O^T = mfma(A=V^T, B=P^T).
// ---------------------------------------------------------------------------
__global__ __launch_bounds__(256) void attn_kernel(const u16* __restrict__ QKV,
                                                   float* __restrict__ aout) {
    __shared__ u16 Klds[64][32];
    __shared__ u16 Vlds[32][68];
    const int t = threadIdx.x;
    const int wv = t >> 6, lane = t & 63;
    const int g = lane >> 4, cc = lane & 15;
    const int h  = blockIdx.x;   // 0..7   (fastest -> determines XCD)
    const int qc = blockIdx.y;   // 0..7  (128 q rows per block)
    const int ba = blockIdx.z;   // 0..15
    const float SCALE = 0.17677669529663687f * 1.44269504088896340736f;
    const size_t base = (size_t)ba * 1024 * 768 + h * 96;

    bf16x8 qf[2];
    #pragma unroll
    for (int s = 0; s < 2; ++s) {
        const u16x8 qr = *reinterpret_cast<const u16x8*>(
            QKV + base + (size_t)(qc * 128 + s * 64 + wv * 16 + cc) * 768 + g * 8);
        #pragma unroll
        for (int j = 0; j < 8; ++j) qf[s][j] = f2bf(bf2f(qr[j]) * SCALE);
    }

    f32x4 o[2][2] = {};
    float m[2] = {-3e38f, -3e38f}, l[2] = {0.f, 0.f};

    const int key_s = t >> 2;
    const int dp    = (t & 3) * 8;
    const u16* kgp = QKV + base + 32 + (size_t)key_s * 768 + dp;
    const u16* vgp = kgp + 32;

    u16x8 kpre = *reinterpret_cast<const u16x8*>(kgp);
    u16x8 vpre = *reinterpret_cast<const u16x8*>(vgp);

    for (int kt = 0; kt < 16; ++kt) {
        __syncthreads();
        *reinterpret_cast<u16x8*>(&Klds[key_s][dp]) = kpre;
        #pragma unroll
        for (int i = 0; i < 8; ++i) Vlds[dp + i][key_s] = vpre[i];
        __syncthreads();
        if (kt < 15) {   // prefetch next tile into regs
            kpre = *reinterpret_cast<const u16x8*>(kgp + (size_t)(kt + 1) * 64 * 768);
            vpre = *reinterpret_cast<const u16x8*>(vgp + (size_t)(kt + 1) * 64 * 768);
        }

        bf16x8 kf[4];
        #pragma unroll
        for (int t16 = 0; t16 < 4; ++t16)
            kf[t16] = *reinterpret_cast<const bf16x8*>(&Klds[t16 * 16 + cc][g * 8]);
        bf16x8 va[2][2];
        #pragma unroll
        for (int hh = 0; hh < 2; ++hh)
            #pragma unroll
            for (int kg = 0; kg < 2; ++kg) {
                const bf16x4 lo = *reinterpret_cast<const bf16x4*>(&Vlds[hh * 16 + cc][kg * 32 + 4 * g]);
                const bf16x4 hi = *reinterpret_cast<const bf16x4*>(&Vlds[hh * 16 + cc][kg * 32 + 16 + 4 * g]);
                va[hh][kg] = __builtin_shufflevector(lo, hi, 0, 1, 2, 3, 4, 5, 6, 7);
            }

        #pragma unroll
        for (int s = 0; s < 2; ++s) {
            const f32x4 z = {};
            f32x4 sc[4];
            #pragma unroll
            for (int t16 = 0; t16 < 4; ++t16)
                sc[t16] = __builtin_amdgcn_mfma_f32_16x16x32_bf16(kf[t16], qf[s], z, 0, 0, 0);

            float mt = sc[0][0];
            #pragma unroll
            for (int t16 = 0; t16 < 4; ++t16)
                #pragma unroll
                for (int r = 0; r < 4; ++r) mt = fmaxf(mt, sc[t16][r]);
            mt = fmaxf(mt, __shfl_xor(mt, 16, 64));
            mt = fmaxf(mt, __shfl_xor(mt, 32, 64));
            const float mn = fmaxf(m[s], mt);
            const float fac = fexp2(m[s] - mn);
            m[s] = mn;

            float p[4][4];
            float rs = 0.f;
            #pragma unroll
            for (int t16 = 0; t16 < 4; ++t16)
                #pragma unroll
                for (int r = 0; r < 4; ++r) {
                    p[t16][r] = fexp2(sc[t16][r] - mn);
                    rs += p[t16][r];
                }
            rs += __shfl_xor(rs, 16, 64);
            rs += __shfl_xor(rs, 32, 64);
            l[s] = l[s] * fac + rs;
            o[s][0] *= fac;
            o[s][1] *= fac;

            union PW { int w[4]; bf16x8 v; } pb0, pb1;
            pb0.w[0] = (int)cvt_pk_bf16(p[0][0], p[0][1]);
            pb0.w[1] = (int)cvt_pk_bf16(p[0][2], p[0][3]);
            pb0.w[2] = (int)cvt_pk_bf16(p[1][0], p[1][1]);
            pb0.w[3] = (int)cvt_pk_bf16(p[1][2], p[1][3]);
            pb1.w[0] = (int)cvt_pk_bf16(p[2][0], p[2][1]);
            pb1.w[1] = (int)cvt_pk_bf16(p[2][2], p[2][3]);
            pb1.w[2] = (int)cvt_pk_bf16(p[3][0], p[3][1]);
            pb1.w[3] = (int)cvt_pk_bf16(p[3][2], p[3][3]);

            o[s][0] = __builtin_amdgcn_mfma_f32_16x16x32_bf16(va[0][0], pb0.v, o[s][0], 0, 0, 0);
            o[s][0] = __builtin_amdgcn_mfma_f32_16x16x32_bf16(va[0][1], pb1.v, o[s][0], 0, 0, 0);
            o[s][1] = __builtin_amdgcn_mfma_f32_16x16x32_bf16(va[1][0], pb0.v, o[s][1], 0, 0, 0);
            o[s][1] = __builtin_amdgcn_mfma_f32_16x16x32_bf16(va[1][1], pb1.v, o[s][1], 0, 0, 0);
        }
    }

    #pragma unroll
    for (int s = 0; s < 2; ++s) {
        const float inv = 1.f / l[s];
        const int q = qc * 128 + s * 64 + wv * 16 + cc;
        float* op = aout + (size_t)(ba * 1024 + q) * 256 + h * 32;
        f32x4 st0 = o[s][0] * inv;
        f32x4 st1 = o[s][1] * inv;
        *reinterpret_cast<f32x4*>(op + 4 * g)      = st0;
        *reinterpret_cast<f32x4*>(op + 16 + 4 * g) = st1;
    }
}

// ---------------------------------------------------------------------------
// Kernel 3: pe_conv.  pebuf[b][c][n] = dwconv7(Vt plane) + b_pe[c].
// ---------------------------------------------------------------------------
__global__ __launch_bounds__(256) void pe_conv(const u16* __restrict__ Vt,
                                               const float* __restrict__ wpe,
                                               const float* __restrict__ bpe,
                                               float* __restrict__ pebuf) {
    __shared__ __align__(16) float P[70][76];
    const int t = threadIdx.x;
    const int bc = blockIdx.x;             // b*256 + c
    const int c = bc & 255;

    {
        f32x4 z = {};
        f32x4* p4 = reinterpret_cast<f32x4*>(&P[0][0]);
        #pragma unroll
        for (int i = 0; i < 6; ++i) {
            const int idx = t + i * 256;
            if (idx < 1330) p4[idx] = z;
        }
    }
    __syncthreads();
    {
        const int row = t >> 2, xo = (t & 3) * 16;
        const u16* src = Vt + (((size_t)bc) << 12) + row * 64 + xo;
        const u16x8 v0 = *reinterpret_cast<const u16x8*>(src);
        const u16x8 v1 = *reinterpret_cast<const u16x8*>(src + 8);
        #pragma unroll
        for (int j = 0; j < 8; ++j) {
            P[row + 3][xo + 3 + j]  = bf2f(v0[j]);
            P[row + 3][xo + 11 + j] = bf2f(v1[j]);
        }
    }
    float wk[49];
    #pragma unroll
    for (int i = 0; i < 49; ++i) wk[i] = wpe[c * 49 + i];
    const float bias = bpe[c];
    __syncthreads();

    const int y = t >> 2, x0 = (t & 3) * 16;
    float acc[16];
    #pragma unroll
    for (int j = 0; j < 16; ++j) acc[j] = bias;

    #pragma unroll
    for (int dy = 0; dy < 7; ++dy) {
        float win[24];
        #pragma unroll
        for (int w4 = 0; w4 < 6; ++w4)
            *reinterpret_cast<f32x4*>(&win[w4 * 4]) =
                *reinterpret_cast<const f32x4*>(&P[y + dy][x0 + w4 * 4]);
        #pragma unroll
        for (int dx = 0; dx < 7; ++dx) {
            const float wgt = wk[dy * 7 + dx];
            #pragma unroll
            for (int xx = 0; xx < 16; ++xx)
                acc[xx] = fmaf(wgt, win[xx + dx], acc[xx]);
        }
    }

    float* dst = pebuf + (((size_t)bc) << 12) + y * 64 + x0;
    #pragma unroll
    for (int w4 = 0; w4 < 4; ++w4)
        *reinterpret_cast<f32x4*>(dst + w4 * 4) =
            *reinterpret_cast<const f32x4*>(&acc[w4 * 4]);
}

// ---------------------------------------------------------------------------
// Kernel 4: proj GEMM.  A = aout[n][k] + pebuf[k][n]; out NCHW via LDS transpose.
// ---------------------------------------------------------------------------
__global__ __launch_bounds__(256) void proj_gemm(const float* __restrict__ A,
                                                 const float* __restrict__ PE,
                                                 const float* __restrict__ W,
                                                 const float* __restrict__ bias,
                                                 float* __restrict__ out) {
    __shared__ union {
        struct { short A[64][40]; short B[64][40]; } s;
        float T[64][65];
    } u;
    const int t = threadIdx.x;
    const int wv = t >> 6, lane = t & 63;
    const int g = lane >> 4, cc = lane & 15;
    const int R0 = blockIdx.x * 64;
    const int b = R0 >> 12, n0 = R0 & 4095;
    const int col0 = blockIdx.y * 64;
    const int a_i  = t >> 2;
    const int a_kp = (t & 3) * 8;
    f32x4 acc[4] = {};

    for (int k0 = 0; k0 < 256; k0 += 32) {
        __syncthreads();
        {
            const float* ap = A + (size_t)(R0 + a_i) * 256 + k0 + a_kp;
            const float4 v0 = *reinterpret_cast<const float4*>(ap);
            const float4 v1 = *reinterpret_cast<const float4*>(ap + 4);
            const float* pp = PE + (((size_t)(b * 256 + k0 + a_kp)) << 12) + n0 + a_i;
            bf16x8 pk;
            pk[0] = f2bf(v0.x + pp[0]);
            pk[1] = f2bf(v0.y + pp[(size_t)1 << 12]);
            pk[2] = f2bf(v0.z + pp[(size_t)2 << 12]);
            pk[3] = f2bf(v0.w + pp[(size_t)3 << 12]);
            pk[4] = f2bf(v1.x + pp[(size_t)4 << 12]);
            pk[5] = f2bf(v1.y + pp[(size_t)5 << 12]);
            pk[6] = f2bf(v1.z + pp[(size_t)6 << 12]);
            pk[7] = f2bf(v1.w + pp[(size_t)7 << 12]);
            *reinterpret_cast<bf16x8*>(&u.s.A[a_i][a_kp]) = pk;

            const float* wp = W + (size_t)(col0 + a_i) * 256 + k0 + a_kp;
            const float4 w0 = *reinterpret_cast<const float4*>(wp);
            const float4 w1 = *reinterpret_cast<const float4*>(wp + 4);
            bf16x8 pw;
            pw[0] = f2bf(w0.x); pw[1] = f2bf(w0.y); pw[2] = f2bf(w0.z); pw[3] = f2bf(w0.w);
            pw[4] = f2bf(w1.x); pw[5] = f2bf(w1.y); pw[6] = f2bf(w1.z); pw[7] = f2bf(w1.w);
            *reinterpret_cast<bf16x8*>(&u.s.B[a_i][a_kp]) = pw;
        }
        __syncthreads();
        const bf16x8 af = *reinterpret_cast<const bf16x8*>(&u.s.A[wv * 16 + cc][g * 8]);
        #pragma unroll
        for (int nt = 0; nt < 4; ++nt) {
            const bf16x8 bfr = *reinterpret_cast<const bf16x8*>(&u.s.B[nt * 16 + cc][g * 8]);
            acc[nt] = __builtin_amdgcn_mfma_f32_16x16x32_bf16(af, bfr, acc[nt], 0, 0, 0);
        }
    }
    __syncthreads();
    #pragma unroll
    for (int nt = 0; nt < 4; ++nt) {
        const float bv = bias[col0 + nt * 16 + cc];
        #pragma unroll
        for (int r = 0; r < 4; ++r)
            u.T[nt * 16 + cc][wv * 16 + g * 4 + r] = acc[nt][r] + bv;
    }
    __syncthreads();
    #pragma unroll
    for (int it = 0; it < 16; ++it) {
        const int idx = it * 256 + t;
        const int ccc = idx >> 6, rr = idx & 63;
        out[(((size_t)(b * 256 + col0 + ccc)) << 12) + n0 + rr] = u.T[ccc][rr];
    }
}

// ---------------------------------------------------------------------------
extern "C" void kernel_launch(void* const* d_in, const int* in_sizes, int n_in,
                              void* d_out, int out_size, void* d_ws, size_t ws_size,
                              hipStream_t stream) {
    const float* x      = (const float*)d_in[0];
    const float* w_qkv  = (const float*)d_in[1];
    const float* b_qkv  = (const float*)d_in[2];
    const float* w_pe   = (const float*)d_in[3];
    const float* b_pe   = (const float*)d_in[4];
    const float* w_proj = (const float*)d_in[5];
    const float* b_proj = (const float*)d_in[6];
    float* out = (float*)d_out;

    char* ws = (char*)d_ws;
    u16*   qkvbuf = (u16*)ws;                                  // 25,165,824 B
    float* aout   = (float*)(ws + 25165824);                   // 16,777,216 B
    u16*   vt     = (u16*)(ws + 41943040);                     //  8,388,608 B
    float* pebuf  = (float*)(ws + 50331648);                   // 16,777,216 B

    qkv_gemm<<<dim3(256, 12), 256, 0, stream>>>(x, w_qkv, b_qkv, qkvbuf, vt);
    attn_kernel<<<dim3(8, 8, 16), 256, 0, stream>>>(qkvbuf, aout);
    pe_conv<<<1024, 256, 0, stream>>>(vt, w_pe, b_pe, pebuf);
    proj_gemm<<<dim3(256, 4), 256, 0, stream>>>(aout, pebuf, w_proj, b_proj, out);
}